// Round 1
// baseline (1061.158 us; speedup 1.0000x reference)
//
#include <hip/hip_runtime.h>
#include <math.h>

#define N_NODES 100000
#define F_IN 128
#define H_DIM 64
#define C_OUT 40

__device__ __forceinline__ float wave_sum64(float v) {
#pragma unroll
    for (int k = 32; k > 0; k >>= 1) v += __shfl_xor(v, k, 64);
    return v;
}

__device__ __forceinline__ float wave_max64(float v) {
#pragma unroll
    for (int k = 32; k > 0; k >>= 1) v = fmaxf(v, __shfl_xor(v, k, 64));
    return v;
}

// ---------------- CSR build ----------------

__global__ void hist_kernel(const int* __restrict__ dst, int* __restrict__ deg, int E) {
    int e = blockIdx.x * blockDim.x + threadIdx.x;
    if (e < E) atomicAdd(&deg[dst[e]], 1);
}

// per-block inclusive scan (256/block) + block sums
__global__ void scan1_kernel(const int* __restrict__ deg, int* __restrict__ incl,
                             int* __restrict__ bsum, int n) {
    __shared__ int s[256];
    int i = blockIdx.x * 256 + threadIdx.x;
    int v = (i < n) ? deg[i] : 0;
    s[threadIdx.x] = v;
    __syncthreads();
#pragma unroll
    for (int off = 1; off < 256; off <<= 1) {
        int t = (threadIdx.x >= off) ? s[threadIdx.x - off] : 0;
        __syncthreads();
        s[threadIdx.x] += t;
        __syncthreads();
    }
    if (i < n) incl[i] = s[threadIdx.x];
    if (threadIdx.x == 255) bsum[blockIdx.x] = s[255];
}

// single-block exclusive scan of block sums (nb <= 512)
__global__ void scan2_kernel(const int* __restrict__ bsum, int* __restrict__ boff, int nb) {
    __shared__ int s[512];
    int v = ((int)threadIdx.x < nb) ? bsum[threadIdx.x] : 0;
    s[threadIdx.x] = v;
    __syncthreads();
#pragma unroll
    for (int off = 1; off < 512; off <<= 1) {
        int t = (threadIdx.x >= off) ? s[threadIdx.x - off] : 0;
        __syncthreads();
        s[threadIdx.x] += t;
        __syncthreads();
    }
    if ((int)threadIdx.x < nb) boff[threadIdx.x] = s[threadIdx.x] - v;  // exclusive
}

__global__ void scan3_kernel(const int* __restrict__ incl, const int* __restrict__ deg,
                             const int* __restrict__ boff, int* __restrict__ rowptr,
                             int* __restrict__ cursor, int n) {
    int i = blockIdx.x * 256 + threadIdx.x;
    if (i < n) {
        int b = i >> 8;
        int excl = boff[b] + incl[i] - deg[i];
        rowptr[i] = excl;
        cursor[i] = excl;
        if (i == n - 1) rowptr[n] = boff[b] + incl[i];
    }
}

__global__ void scatter_kernel(const int* __restrict__ src, const int* __restrict__ dst,
                               int* __restrict__ cursor, int* __restrict__ ssrc, int E) {
    int e = blockIdx.x * blockDim.x + threadIdx.x;
    if (e < E) {
        int d = dst[e];
        int p = atomicAdd(&cursor[d], 1);
        ssrc[p] = src[e];
    }
}

// ---------------- lin1: h = relu(x @ W1 + b1), plus rnorm ----------------
// one wave per row; lane = output column (64 cols = 64 lanes)
__global__ void lin1_kernel(const float* __restrict__ x, const float* __restrict__ W1,
                            const float* __restrict__ b1, float* __restrict__ h,
                            float* __restrict__ rn, int n) {
    int wid = (blockIdx.x * blockDim.x + threadIdx.x) >> 6;
    int lane = threadIdx.x & 63;
    if (wid >= n) return;
    const float* xr = x + (size_t)wid * F_IN;
    float acc = b1[lane];
#pragma unroll
    for (int k = 0; k < F_IN; k += 4) {
        float4 xv = *(const float4*)(xr + k);  // wave-uniform address -> broadcast
        acc = fmaf(xv.x, W1[(k + 0) * H_DIM + lane], acc);
        acc = fmaf(xv.y, W1[(k + 1) * H_DIM + lane], acc);
        acc = fmaf(xv.z, W1[(k + 2) * H_DIM + lane], acc);
        acc = fmaf(xv.w, W1[(k + 3) * H_DIM + lane], acc);
    }
    acc = fmaxf(acc, 0.0f);
    h[(size_t)wid * H_DIM + lane] = acc;
    float ss = wave_sum64(acc * acc);
    if (lane == 0) rn[wid] = 1.0f / fmaxf(sqrtf(ss), 1e-12f);
}

// ---------------- AGNN layer: wave per dst node ----------------
__global__ void agnn_kernel(const float* __restrict__ h, const float* __restrict__ rnorm,
                            const int* __restrict__ rowptr, const int* __restrict__ ssrc,
                            float* __restrict__ hout, float* __restrict__ rnout, int n) {
    int wid = (blockIdx.x * blockDim.x + threadIdx.x) >> 6;
    int lane = threadIdx.x & 63;
    if (wid >= n) return;

    float hd = h[(size_t)wid * H_DIM + lane];
    float rni = rnorm[wid];

    // self loop: logit = ||h||^2 * rni^2
    float dself = wave_sum64(hd * hd);
    float wself = __expf(dself * rni * rni);
    float acc = wself * hd;
    float sw = wself;

    int e = rowptr[wid];
    int end = rowptr[wid + 1];
    for (; e + 1 < end; e += 2) {
        int s0 = ssrc[e];
        int s1 = ssrc[e + 1];
        float hv0 = h[(size_t)s0 * H_DIM + lane];
        float hv1 = h[(size_t)s1 * H_DIM + lane];
        float rn0 = rnorm[s0];
        float rn1 = rnorm[s1];
        float d0 = wave_sum64(hv0 * hd);
        float d1 = wave_sum64(hv1 * hd);
        float w0 = __expf(d0 * rni * rn0);
        float w1 = __expf(d1 * rni * rn1);
        acc = fmaf(w0, hv0, acc);
        acc = fmaf(w1, hv1, acc);
        sw += w0 + w1;
    }
    if (e < end) {
        int s0 = ssrc[e];
        float hv0 = h[(size_t)s0 * H_DIM + lane];
        float rn0 = rnorm[s0];
        float d0 = wave_sum64(hv0 * hd);
        float w0 = __expf(d0 * rni * rn0);
        acc = fmaf(w0, hv0, acc);
        sw += w0;
    }

    float o = acc / sw;
    hout[(size_t)wid * H_DIM + lane] = o;
    float ss = wave_sum64(o * o);
    if (lane == 0) rnout[wid] = 1.0f / fmaxf(sqrtf(ss), 1e-12f);
}

// ---------------- lin2 + log_softmax: wave per row ----------------
__global__ void lin2_kernel(const float* __restrict__ h, const float* __restrict__ W2,
                            const float* __restrict__ b2, float* __restrict__ out, int n) {
    int wid = (blockIdx.x * blockDim.x + threadIdx.x) >> 6;
    int lane = threadIdx.x & 63;
    if (wid >= n) return;
    const float* hr = h + (size_t)wid * H_DIM;
    float acc = -INFINITY;
    if (lane < C_OUT) {
        acc = b2[lane];
#pragma unroll
        for (int k = 0; k < H_DIM; k += 4) {
            float4 hv = *(const float4*)(hr + k);  // wave-uniform -> broadcast
            acc = fmaf(hv.x, W2[(k + 0) * C_OUT + lane], acc);
            acc = fmaf(hv.y, W2[(k + 1) * C_OUT + lane], acc);
            acc = fmaf(hv.z, W2[(k + 2) * C_OUT + lane], acc);
            acc = fmaf(hv.w, W2[(k + 3) * C_OUT + lane], acc);
        }
    }
    float m = wave_max64(acc);
    float e = (lane < C_OUT) ? __expf(acc - m) : 0.0f;
    float s = wave_sum64(e);
    if (lane < C_OUT) out[(size_t)wid * C_OUT + lane] = acc - m - logf(s);
}

// ---------------- launch ----------------

extern "C" void kernel_launch(void* const* d_in, const int* in_sizes, int n_in,
                              void* d_out, int out_size, void* d_ws, size_t ws_size,
                              hipStream_t stream) {
    const float* x = (const float*)d_in[0];
    const float* W1 = (const float*)d_in[1];
    const float* b1 = (const float*)d_in[2];
    const float* W2 = (const float*)d_in[3];
    const float* b2 = (const float*)d_in[4];
    const int* ei = (const int*)d_in[5];

    const int N = in_sizes[0] / F_IN;      // 100000
    const int E = in_sizes[5] / 2;         // 1600000
    const int* src = ei;
    const int* dst = ei + E;

    // workspace carve (all 256B aligned)
    char* w = (char*)d_ws;
    auto carve = [&](size_t bytes) {
        char* p = w;
        w += (bytes + 255) & ~(size_t)255;
        return p;
    };
    float* h1 = (float*)carve((size_t)N * H_DIM * 4);
    float* h2 = (float*)carve((size_t)N * H_DIM * 4);
    float* rn1 = (float*)carve((size_t)N * 4);
    float* rn2 = (float*)carve((size_t)N * 4);
    int* deg = (int*)carve((size_t)N * 4);
    int* incl = (int*)carve((size_t)N * 4);
    int* rowptr = (int*)carve((size_t)(N + 1) * 4);
    int* cursor = (int*)carve((size_t)N * 4);
    int* bsum = (int*)carve(1024 * 4);
    int* boff = (int*)carve(1024 * 4);
    int* ssrc = (int*)carve((size_t)E * 4);

    const int nb = (N + 255) / 256;  // 391 blocks for scans

    // CSR build
    hipMemsetAsync(deg, 0, (size_t)N * 4, stream);
    hist_kernel<<<(E + 255) / 256, 256, 0, stream>>>(dst, deg, E);
    scan1_kernel<<<nb, 256, 0, stream>>>(deg, incl, bsum, N);
    scan2_kernel<<<1, 512, 0, stream>>>(bsum, boff, nb);
    scan3_kernel<<<nb, 256, 0, stream>>>(incl, deg, boff, rowptr, cursor, N);
    scatter_kernel<<<(E + 255) / 256, 256, 0, stream>>>(src, dst, cursor, ssrc, E);

    // lin1 (+rnorm)
    {
        int threads = N * 64;
        lin1_kernel<<<(threads + 255) / 256, 256, 0, stream>>>(x, W1, b1, h1, rn1, N);
    }

    // 4 AGNN layers, ping-pong
    {
        int threads = N * 64;
        int blocks = (threads + 255) / 256;
        agnn_kernel<<<blocks, 256, 0, stream>>>(h1, rn1, rowptr, ssrc, h2, rn2, N);
        agnn_kernel<<<blocks, 256, 0, stream>>>(h2, rn2, rowptr, ssrc, h1, rn1, N);
        agnn_kernel<<<blocks, 256, 0, stream>>>(h1, rn1, rowptr, ssrc, h2, rn2, N);
        agnn_kernel<<<blocks, 256, 0, stream>>>(h2, rn2, rowptr, ssrc, h1, rn1, N);
    }

    // lin2 + log_softmax
    {
        int threads = N * 64;
        lin2_kernel<<<(threads + 255) / 256, 256, 0, stream>>>(h1, W2, b2, (float*)d_out, N);
    }
}

// Round 2
// 918.328 us; speedup vs baseline: 1.1555x; 1.1555x over previous
//
#include <hip/hip_runtime.h>
#include <math.h>

#define N_NODES 100000
#define F_IN 128
#define H_DIM 64
#define C_OUT 40
#define ROWS 8

__device__ __forceinline__ float wave_sum64(float v) {
#pragma unroll
    for (int k = 32; k > 0; k >>= 1) v += __shfl_xor(v, k, 64);
    return v;
}

__device__ __forceinline__ float wave_max64(float v) {
#pragma unroll
    for (int k = 32; k > 0; k >>= 1) v = fmaxf(v, __shfl_xor(v, k, 64));
    return v;
}

// ---------------- CSR build ----------------

__global__ void hist_kernel(const int* __restrict__ dst, int* __restrict__ deg, int E) {
    int e = blockIdx.x * blockDim.x + threadIdx.x;
    if (e < E) atomicAdd(&deg[dst[e]], 1);
}

__global__ void scan1_kernel(const int* __restrict__ deg, int* __restrict__ incl,
                             int* __restrict__ bsum, int n) {
    __shared__ int s[256];
    int i = blockIdx.x * 256 + threadIdx.x;
    int v = (i < n) ? deg[i] : 0;
    s[threadIdx.x] = v;
    __syncthreads();
#pragma unroll
    for (int off = 1; off < 256; off <<= 1) {
        int t = (threadIdx.x >= off) ? s[threadIdx.x - off] : 0;
        __syncthreads();
        s[threadIdx.x] += t;
        __syncthreads();
    }
    if (i < n) incl[i] = s[threadIdx.x];
    if (threadIdx.x == 255) bsum[blockIdx.x] = s[255];
}

__global__ void scan2_kernel(const int* __restrict__ bsum, int* __restrict__ boff, int nb) {
    __shared__ int s[512];
    int v = ((int)threadIdx.x < nb) ? bsum[threadIdx.x] : 0;
    s[threadIdx.x] = v;
    __syncthreads();
#pragma unroll
    for (int off = 1; off < 512; off <<= 1) {
        int t = (threadIdx.x >= off) ? s[threadIdx.x - off] : 0;
        __syncthreads();
        s[threadIdx.x] += t;
        __syncthreads();
    }
    if ((int)threadIdx.x < nb) boff[threadIdx.x] = s[threadIdx.x] - v;
}

__global__ void scan3_kernel(const int* __restrict__ incl, const int* __restrict__ deg,
                             const int* __restrict__ boff, int* __restrict__ rowptr,
                             int* __restrict__ cursor, int n) {
    int i = blockIdx.x * 256 + threadIdx.x;
    if (i < n) {
        int b = i >> 8;
        int excl = boff[b] + incl[i] - deg[i];
        rowptr[i] = excl;
        cursor[i] = excl;
        if (i == n - 1) rowptr[n] = boff[b] + incl[i];
    }
}

__global__ void scatter_kernel(const int* __restrict__ src, const int* __restrict__ dst,
                               int* __restrict__ cursor, int* __restrict__ ssrc, int E) {
    int e = blockIdx.x * blockDim.x + threadIdx.x;
    if (e < E) {
        int d = dst[e];
        int p = atomicAdd(&cursor[d], 1);
        ssrc[p] = src[e];
    }
}

// ---------------- lin1: 8 rows per wave, lane = output col ----------------
__global__ void lin1_kernel(const float* __restrict__ x, const float* __restrict__ W1,
                            const float* __restrict__ b1, float* __restrict__ h,
                            float* __restrict__ rn, int n) {
    int wid = (blockIdx.x * blockDim.x + threadIdx.x) >> 6;
    int lane = threadIdx.x & 63;
    int r0 = wid * ROWS;
    if (r0 >= n) return;
    const float* xr = x + (size_t)r0 * F_IN;

    float bl = b1[lane];
    float acc[ROWS];
#pragma unroll
    for (int j = 0; j < ROWS; j++) acc[j] = bl;

#pragma unroll 2
    for (int k = 0; k < F_IN; k += 4) {
        float4 xv[ROWS];
#pragma unroll
        for (int j = 0; j < ROWS; j++) xv[j] = *(const float4*)(xr + j * F_IN + k);
        float w0 = W1[(k + 0) * H_DIM + lane];
        float w1 = W1[(k + 1) * H_DIM + lane];
        float w2 = W1[(k + 2) * H_DIM + lane];
        float w3 = W1[(k + 3) * H_DIM + lane];
#pragma unroll
        for (int j = 0; j < ROWS; j++) {
            acc[j] = fmaf(xv[j].x, w0, acc[j]);
            acc[j] = fmaf(xv[j].y, w1, acc[j]);
            acc[j] = fmaf(xv[j].z, w2, acc[j]);
            acc[j] = fmaf(xv[j].w, w3, acc[j]);
        }
    }

#pragma unroll
    for (int j = 0; j < ROWS; j++) {
        float a = fmaxf(acc[j], 0.0f);
        h[(size_t)(r0 + j) * H_DIM + lane] = a;
        float ss = wave_sum64(a * a);
        if (lane == 0) rn[r0 + j] = 1.0f / fmaxf(sqrtf(ss), 1e-12f);
    }
}

// ---------------- AGNN layer: wave per dst node, 4-edge unrolled ----------------
__global__ void agnn_kernel(const float* __restrict__ h, const float* __restrict__ rnorm,
                            const int* __restrict__ rowptr, const int* __restrict__ ssrc,
                            float* __restrict__ hout, float* __restrict__ rnout, int n) {
    int wid = (blockIdx.x * blockDim.x + threadIdx.x) >> 6;
    int lane = threadIdx.x & 63;
    if (wid >= n) return;

    float hd = h[(size_t)wid * H_DIM + lane];
    float rni = rnorm[wid];

    // self loop
    float dself = wave_sum64(hd * hd);
    float sw = __expf(dself * rni * rni);
    float acc = sw * hd;

    int e = rowptr[wid];
    int end = rowptr[wid + 1];

    for (; e + 3 < end; e += 4) {
        int s0 = ssrc[e + 0];
        int s1 = ssrc[e + 1];
        int s2 = ssrc[e + 2];
        int s3 = ssrc[e + 3];
        float hv0 = h[(size_t)s0 * H_DIM + lane];
        float hv1 = h[(size_t)s1 * H_DIM + lane];
        float hv2 = h[(size_t)s2 * H_DIM + lane];
        float hv3 = h[(size_t)s3 * H_DIM + lane];
        float rn0 = rnorm[s0];
        float rn1 = rnorm[s1];
        float rn2 = rnorm[s2];
        float rn3 = rnorm[s3];
        float d0 = hv0 * hd;
        float d1 = hv1 * hd;
        float d2 = hv2 * hd;
        float d3 = hv3 * hd;
        // four butterflies in lockstep -> independent ds_swizzle chains pipeline
#pragma unroll
        for (int k = 32; k > 0; k >>= 1) {
            d0 += __shfl_xor(d0, k, 64);
            d1 += __shfl_xor(d1, k, 64);
            d2 += __shfl_xor(d2, k, 64);
            d3 += __shfl_xor(d3, k, 64);
        }
        float w0 = __expf(d0 * rni * rn0);
        float w1 = __expf(d1 * rni * rn1);
        float w2 = __expf(d2 * rni * rn2);
        float w3 = __expf(d3 * rni * rn3);
        acc = fmaf(w0, hv0, acc);
        acc = fmaf(w1, hv1, acc);
        acc = fmaf(w2, hv2, acc);
        acc = fmaf(w3, hv3, acc);
        sw += (w0 + w1) + (w2 + w3);
    }
    for (; e < end; e++) {
        int s0 = ssrc[e];
        float hv0 = h[(size_t)s0 * H_DIM + lane];
        float rn0 = rnorm[s0];
        float d0 = wave_sum64(hv0 * hd);
        float w0 = __expf(d0 * rni * rn0);
        acc = fmaf(w0, hv0, acc);
        sw += w0;
    }

    float o = acc / sw;
    hout[(size_t)wid * H_DIM + lane] = o;
    float ss = wave_sum64(o * o);
    if (lane == 0) rnout[wid] = 1.0f / fmaxf(sqrtf(ss), 1e-12f);
}

// ---------------- lin2 + log_softmax: 8 rows per wave ----------------
__global__ void lin2_kernel(const float* __restrict__ h, const float* __restrict__ W2,
                            const float* __restrict__ b2, float* __restrict__ out, int n) {
    int wid = (blockIdx.x * blockDim.x + threadIdx.x) >> 6;
    int lane = threadIdx.x & 63;
    int r0 = wid * ROWS;
    if (r0 >= n) return;
    const float* hr = h + (size_t)r0 * H_DIM;

    float acc[ROWS];
    if (lane < C_OUT) {
        float bl = b2[lane];
#pragma unroll
        for (int j = 0; j < ROWS; j++) acc[j] = bl;
#pragma unroll 2
        for (int k = 0; k < H_DIM; k += 4) {
            float4 hv[ROWS];
#pragma unroll
            for (int j = 0; j < ROWS; j++) hv[j] = *(const float4*)(hr + j * H_DIM + k);
            float w0 = W2[(k + 0) * C_OUT + lane];
            float w1 = W2[(k + 1) * C_OUT + lane];
            float w2 = W2[(k + 2) * C_OUT + lane];
            float w3 = W2[(k + 3) * C_OUT + lane];
#pragma unroll
            for (int j = 0; j < ROWS; j++) {
                acc[j] = fmaf(hv[j].x, w0, acc[j]);
                acc[j] = fmaf(hv[j].y, w1, acc[j]);
                acc[j] = fmaf(hv[j].z, w2, acc[j]);
                acc[j] = fmaf(hv[j].w, w3, acc[j]);
            }
        }
    } else {
#pragma unroll
        for (int j = 0; j < ROWS; j++) acc[j] = -INFINITY;
    }

#pragma unroll
    for (int j = 0; j < ROWS; j++) {
        float m = wave_max64(acc[j]);
        float e = (lane < C_OUT) ? __expf(acc[j] - m) : 0.0f;
        float s = wave_sum64(e);
        if (lane < C_OUT) out[(size_t)(r0 + j) * C_OUT + lane] = acc[j] - m - logf(s);
    }
}

// ---------------- launch ----------------

extern "C" void kernel_launch(void* const* d_in, const int* in_sizes, int n_in,
                              void* d_out, int out_size, void* d_ws, size_t ws_size,
                              hipStream_t stream) {
    const float* x = (const float*)d_in[0];
    const float* W1 = (const float*)d_in[1];
    const float* b1 = (const float*)d_in[2];
    const float* W2 = (const float*)d_in[3];
    const float* b2 = (const float*)d_in[4];
    const int* ei = (const int*)d_in[5];

    const int N = in_sizes[0] / F_IN;      // 100000
    const int E = in_sizes[5] / 2;         // 1600000
    const int* src = ei;
    const int* dst = ei + E;

    char* w = (char*)d_ws;
    auto carve = [&](size_t bytes) {
        char* p = w;
        w += (bytes + 255) & ~(size_t)255;
        return p;
    };
    float* h1 = (float*)carve((size_t)N * H_DIM * 4);
    float* h2 = (float*)carve((size_t)N * H_DIM * 4);
    float* rn1 = (float*)carve((size_t)N * 4);
    float* rn2 = (float*)carve((size_t)N * 4);
    int* deg = (int*)carve((size_t)N * 4);
    int* incl = (int*)carve((size_t)N * 4);
    int* rowptr = (int*)carve((size_t)(N + 1) * 4);
    int* cursor = (int*)carve((size_t)N * 4);
    int* bsum = (int*)carve(1024 * 4);
    int* boff = (int*)carve(1024 * 4);
    int* ssrc = (int*)carve((size_t)E * 4);

    const int nb = (N + 255) / 256;

    // CSR build
    hipMemsetAsync(deg, 0, (size_t)N * 4, stream);
    hist_kernel<<<(E + 255) / 256, 256, 0, stream>>>(dst, deg, E);
    scan1_kernel<<<nb, 256, 0, stream>>>(deg, incl, bsum, N);
    scan2_kernel<<<1, 512, 0, stream>>>(bsum, boff, nb);
    scan3_kernel<<<nb, 256, 0, stream>>>(incl, deg, boff, rowptr, cursor, N);
    scatter_kernel<<<(E + 255) / 256, 256, 0, stream>>>(src, dst, cursor, ssrc, E);

    // lin1 (+rnorm): 8 rows/wave -> N/8 waves
    {
        int waves = (N + ROWS - 1) / ROWS;
        lin1_kernel<<<(waves * 64 + 255) / 256, 256, 0, stream>>>(x, W1, b1, h1, rn1, N);
    }

    // 4 AGNN layers, ping-pong
    {
        int threads = N * 64;
        int blocks = (threads + 255) / 256;
        agnn_kernel<<<blocks, 256, 0, stream>>>(h1, rn1, rowptr, ssrc, h2, rn2, N);
        agnn_kernel<<<blocks, 256, 0, stream>>>(h2, rn2, rowptr, ssrc, h1, rn1, N);
        agnn_kernel<<<blocks, 256, 0, stream>>>(h1, rn1, rowptr, ssrc, h2, rn2, N);
        agnn_kernel<<<blocks, 256, 0, stream>>>(h2, rn2, rowptr, ssrc, h1, rn1, N);
    }

    // lin2 + log_softmax: 8 rows/wave
    {
        int waves = (N + ROWS - 1) / ROWS;
        lin2_kernel<<<(waves * 64 + 255) / 256, 256, 0, stream>>>(h1, W2, b2, (float*)d_out, N);
    }
}

// Round 3
// 637.370 us; speedup vs baseline: 1.6649x; 1.4408x over previous
//
#include <hip/hip_runtime.h>
#include <math.h>

#define F_IN 128
#define H_DIM 64
#define C_OUT 40

__device__ __forceinline__ float dot4(float4 a, float4 b) {
    return fmaf(a.x, b.x, fmaf(a.y, b.y, fmaf(a.z, b.z, a.w * b.w)));
}

// ---------------- CSR build ----------------

__global__ void hist_kernel(const int* __restrict__ dst, int* __restrict__ deg, int E) {
    int e = blockIdx.x * blockDim.x + threadIdx.x;
    if (e < E) atomicAdd(&deg[dst[e]], 1);
}

__global__ void scan1_kernel(const int* __restrict__ deg, int* __restrict__ incl,
                             int* __restrict__ bsum, int n) {
    __shared__ int s[256];
    int i = blockIdx.x * 256 + threadIdx.x;
    int v = (i < n) ? deg[i] : 0;
    s[threadIdx.x] = v;
    __syncthreads();
#pragma unroll
    for (int off = 1; off < 256; off <<= 1) {
        int t = (threadIdx.x >= off) ? s[threadIdx.x - off] : 0;
        __syncthreads();
        s[threadIdx.x] += t;
        __syncthreads();
    }
    if (i < n) incl[i] = s[threadIdx.x];
    if (threadIdx.x == 255) bsum[blockIdx.x] = s[255];
}

__global__ void scan2_kernel(const int* __restrict__ bsum, int* __restrict__ boff, int nb) {
    __shared__ int s[512];
    int v = ((int)threadIdx.x < nb) ? bsum[threadIdx.x] : 0;
    s[threadIdx.x] = v;
    __syncthreads();
#pragma unroll
    for (int off = 1; off < 512; off <<= 1) {
        int t = (threadIdx.x >= off) ? s[threadIdx.x - off] : 0;
        __syncthreads();
        s[threadIdx.x] += t;
        __syncthreads();
    }
    if ((int)threadIdx.x < nb) boff[threadIdx.x] = s[threadIdx.x] - v;
}

__global__ void scan3_kernel(const int* __restrict__ incl, const int* __restrict__ deg,
                             const int* __restrict__ boff, int* __restrict__ rowptr,
                             int* __restrict__ cursor, int n) {
    int i = blockIdx.x * 256 + threadIdx.x;
    if (i < n) {
        int b = i >> 8;
        int excl = boff[b] + incl[i] - deg[i];
        rowptr[i] = excl;
        cursor[i] = excl;
        if (i == n - 1) rowptr[n] = boff[b] + incl[i];
    }
}

__global__ void scatter_kernel(const int* __restrict__ src, const int* __restrict__ dst,
                               int* __restrict__ cursor, int* __restrict__ ssrc, int E) {
    int e = blockIdx.x * blockDim.x + threadIdx.x;
    if (e < E) {
        int d = dst[e];
        int p = atomicAdd(&cursor[d], 1);
        ssrc[p] = src[e];
    }
}

// ---------------- lin1: LDS-staged tile, 32 rows/block, 8 rows/wave ----------------
__global__ void __launch_bounds__(256) lin1_kernel(
        const float* __restrict__ x, const float* __restrict__ W1,
        const float* __restrict__ b1, float* __restrict__ h,
        float* __restrict__ rn, int n) {
    __shared__ float sx[32 * F_IN];  // 16 KB
    int tid = threadIdx.x;
    int r0 = blockIdx.x * 32;
    int rows = min(32, n - r0);

    // coalesced stage: rows*F_IN floats = rows*32 float4
    {
        const float4* xg = (const float4*)(x + (size_t)r0 * F_IN);
        float4* sx4 = (float4*)sx;
        int tot = rows * (F_IN / 4);
        for (int i = tid; i < tot; i += 256) sx4[i] = xg[i];
    }
    __syncthreads();

    int wave = tid >> 6, lane = tid & 63;
    int rbase = wave * 8;
    float bl = b1[lane];
    float acc[8];
#pragma unroll
    for (int j = 0; j < 8; j++) acc[j] = bl;

    const float4* sx4 = (const float4*)sx;
#pragma unroll 2
    for (int k = 0; k < F_IN; k += 4) {
        float w0 = W1[(k + 0) * H_DIM + lane];
        float w1 = W1[(k + 1) * H_DIM + lane];
        float w2 = W1[(k + 2) * H_DIM + lane];
        float w3 = W1[(k + 3) * H_DIM + lane];
#pragma unroll
        for (int j = 0; j < 8; j++) {
            float4 xv = sx4[(rbase + j) * (F_IN / 4) + (k >> 2)];  // broadcast ds_read_b128
            acc[j] = fmaf(xv.x, w0, acc[j]);
            acc[j] = fmaf(xv.y, w1, acc[j]);
            acc[j] = fmaf(xv.z, w2, acc[j]);
            acc[j] = fmaf(xv.w, w3, acc[j]);
        }
    }

#pragma unroll
    for (int j = 0; j < 8; j++) {
        int r = rbase + j;
        if (r >= rows) break;
        float a = fmaxf(acc[j], 0.0f);
        h[(size_t)(r0 + r) * H_DIM + lane] = a;
        float ss = a * a;
#pragma unroll
        for (int k = 1; k < 64; k <<= 1) ss += __shfl_xor(ss, k, 64);
        if (lane == 0) rn[r0 + r] = 1.0f / fmaxf(sqrtf(ss), 1e-12f);
    }
}

// ---------------- AGNN layer: wave per dst, 16 lanes/edge, 4 edges at a time ----------------
__global__ void __launch_bounds__(256) agnn_kernel(
        const float* __restrict__ h, const float* __restrict__ rnorm,
        const int* __restrict__ rowptr, const int* __restrict__ ssrc,
        float* __restrict__ hout, float* __restrict__ rnout, int n) {
    int wid = (blockIdx.x * blockDim.x + threadIdx.x) >> 6;
    int t = threadIdx.x & 63;
    if (wid >= n) return;
    int g = t >> 4;        // edge group 0..3
    int sub = t & 15;      // feature chunk 0..15 (4 floats each)

    float4 hdv = *(const float4*)(h + (size_t)wid * H_DIM + sub * 4);
    float rni = rnorm[wid];

    // self loop (each 16-lane group holds the full row)
    float dself = dot4(hdv, hdv);
#pragma unroll
    for (int k = 1; k < 16; k <<= 1) dself += __shfl_xor(dself, k, 64);
    float wself = __expf(dself * rni * rni);

    float4 acc;
    float sw;
    if (g == 0) {
        acc.x = wself * hdv.x; acc.y = wself * hdv.y;
        acc.z = wself * hdv.z; acc.w = wself * hdv.w;
        sw = wself;
    } else {
        acc.x = acc.y = acc.z = acc.w = 0.0f;
        sw = 0.0f;
    }

    int base = rowptr[wid];
    int end = rowptr[wid + 1];
    int e = base + g;

    // 2 edges per group per iteration -> 8 gathers in flight per wave
    for (; e + 4 < end; e += 8) {
        int s0 = ssrc[e];
        int s1 = ssrc[e + 4];
        float4 hv0 = *(const float4*)(h + (size_t)s0 * H_DIM + sub * 4);
        float4 hv1 = *(const float4*)(h + (size_t)s1 * H_DIM + sub * 4);
        float rn0 = rnorm[s0];
        float rn1 = rnorm[s1];
        float d0 = dot4(hv0, hdv);
        float d1 = dot4(hv1, hdv);
#pragma unroll
        for (int k = 1; k < 16; k <<= 1) {
            d0 += __shfl_xor(d0, k, 64);
            d1 += __shfl_xor(d1, k, 64);
        }
        float w0 = __expf(d0 * rni * rn0);
        float w1 = __expf(d1 * rni * rn1);
        acc.x = fmaf(w0, hv0.x, fmaf(w1, hv1.x, acc.x));
        acc.y = fmaf(w0, hv0.y, fmaf(w1, hv1.y, acc.y));
        acc.z = fmaf(w0, hv0.z, fmaf(w1, hv1.z, acc.z));
        acc.w = fmaf(w0, hv0.w, fmaf(w1, hv1.w, acc.w));
        sw += w0 + w1;
    }
    for (; e < end; e += 4) {
        int s0 = ssrc[e];
        float4 hv0 = *(const float4*)(h + (size_t)s0 * H_DIM + sub * 4);
        float rn0 = rnorm[s0];
        float d0 = dot4(hv0, hdv);
#pragma unroll
        for (int k = 1; k < 16; k <<= 1) d0 += __shfl_xor(d0, k, 64);
        float w0 = __expf(d0 * rni * rn0);
        acc.x = fmaf(w0, hv0.x, acc.x);
        acc.y = fmaf(w0, hv0.y, acc.y);
        acc.z = fmaf(w0, hv0.z, acc.z);
        acc.w = fmaf(w0, hv0.w, acc.w);
        sw += w0;
    }

    // combine the 4 groups
#pragma unroll
    for (int k = 16; k < 64; k <<= 1) {
        acc.x += __shfl_xor(acc.x, k, 64);
        acc.y += __shfl_xor(acc.y, k, 64);
        acc.z += __shfl_xor(acc.z, k, 64);
        acc.w += __shfl_xor(acc.w, k, 64);
        sw += __shfl_xor(sw, k, 64);
    }
    float inv = 1.0f / sw;
    float4 o;
    o.x = acc.x * inv; o.y = acc.y * inv; o.z = acc.z * inv; o.w = acc.w * inv;
    if (g == 0) *(float4*)(hout + (size_t)wid * H_DIM + sub * 4) = o;

    float ss = dot4(o, o);
#pragma unroll
    for (int k = 1; k < 16; k <<= 1) ss += __shfl_xor(ss, k, 64);
    if (t == 0) rnout[wid] = 1.0f / fmaxf(sqrtf(ss), 1e-12f);
}

// ---------------- lin2 + log_softmax: LDS-staged, 32 rows/block ----------------
__global__ void __launch_bounds__(256) lin2_kernel(
        const float* __restrict__ h, const float* __restrict__ W2,
        const float* __restrict__ b2, float* __restrict__ out, int n) {
    __shared__ float sh[32 * H_DIM];  // 8 KB
    int tid = threadIdx.x;
    int r0 = blockIdx.x * 32;
    int rows = min(32, n - r0);

    {
        const float4* hg = (const float4*)(h + (size_t)r0 * H_DIM);
        float4* sh4 = (float4*)sh;
        int tot = rows * (H_DIM / 4);
        for (int i = tid; i < tot; i += 256) sh4[i] = hg[i];
    }
    __syncthreads();

    int wave = tid >> 6, lane = tid & 63;
    int rbase = wave * 8;
    const float4* sh4 = (const float4*)sh;

    float acc[8];
    if (lane < C_OUT) {
        float bl = b2[lane];
#pragma unroll
        for (int j = 0; j < 8; j++) acc[j] = bl;
#pragma unroll 2
        for (int k = 0; k < H_DIM; k += 4) {
            float w0 = W2[(k + 0) * C_OUT + lane];
            float w1 = W2[(k + 1) * C_OUT + lane];
            float w2 = W2[(k + 2) * C_OUT + lane];
            float w3 = W2[(k + 3) * C_OUT + lane];
#pragma unroll
            for (int j = 0; j < 8; j++) {
                float4 hv = sh4[(rbase + j) * (H_DIM / 4) + (k >> 2)];
                acc[j] = fmaf(hv.x, w0, acc[j]);
                acc[j] = fmaf(hv.y, w1, acc[j]);
                acc[j] = fmaf(hv.z, w2, acc[j]);
                acc[j] = fmaf(hv.w, w3, acc[j]);
            }
        }
    } else {
#pragma unroll
        for (int j = 0; j < 8; j++) acc[j] = -INFINITY;
    }

#pragma unroll
    for (int j = 0; j < 8; j++) {
        int r = rbase + j;
        if (r >= rows) break;
        float m = acc[j];
#pragma unroll
        for (int k = 1; k < 64; k <<= 1) m = fmaxf(m, __shfl_xor(m, k, 64));
        float e = (lane < C_OUT) ? __expf(acc[j] - m) : 0.0f;
        float s = e;
#pragma unroll
        for (int k = 1; k < 64; k <<= 1) s += __shfl_xor(s, k, 64);
        if (lane < C_OUT) out[(size_t)(r0 + r) * C_OUT + lane] = acc[j] - m - logf(s);
    }
}

// ---------------- launch ----------------

extern "C" void kernel_launch(void* const* d_in, const int* in_sizes, int n_in,
                              void* d_out, int out_size, void* d_ws, size_t ws_size,
                              hipStream_t stream) {
    const float* x = (const float*)d_in[0];
    const float* W1 = (const float*)d_in[1];
    const float* b1 = (const float*)d_in[2];
    const float* W2 = (const float*)d_in[3];
    const float* b2 = (const float*)d_in[4];
    const int* ei = (const int*)d_in[5];

    const int N = in_sizes[0] / F_IN;      // 100000
    const int E = in_sizes[5] / 2;         // 1600000
    const int* src = ei;
    const int* dst = ei + E;

    char* w = (char*)d_ws;
    auto carve = [&](size_t bytes) {
        char* p = w;
        w += (bytes + 255) & ~(size_t)255;
        return p;
    };
    float* h1 = (float*)carve((size_t)N * H_DIM * 4);
    float* h2 = (float*)carve((size_t)N * H_DIM * 4);
    float* rn1 = (float*)carve((size_t)N * 4);
    float* rn2 = (float*)carve((size_t)N * 4);
    int* deg = (int*)carve((size_t)N * 4);
    int* incl = (int*)carve((size_t)N * 4);
    int* rowptr = (int*)carve((size_t)(N + 1) * 4);
    int* cursor = (int*)carve((size_t)N * 4);
    int* bsum = (int*)carve(1024 * 4);
    int* boff = (int*)carve(1024 * 4);
    int* ssrc = (int*)carve((size_t)E * 4);

    const int nb = (N + 255) / 256;

    // CSR build
    hipMemsetAsync(deg, 0, (size_t)N * 4, stream);
    hist_kernel<<<(E + 255) / 256, 256, 0, stream>>>(dst, deg, E);
    scan1_kernel<<<nb, 256, 0, stream>>>(deg, incl, bsum, N);
    scan2_kernel<<<1, 512, 0, stream>>>(bsum, boff, nb);
    scan3_kernel<<<nb, 256, 0, stream>>>(incl, deg, boff, rowptr, cursor, N);
    scatter_kernel<<<(E + 255) / 256, 256, 0, stream>>>(src, dst, cursor, ssrc, E);

    // lin1 (+rnorm)
    lin1_kernel<<<(N + 31) / 32, 256, 0, stream>>>(x, W1, b1, h1, rn1, N);

    // 4 AGNN layers, ping-pong
    {
        int blocks = (N * 64 + 255) / 256;
        agnn_kernel<<<blocks, 256, 0, stream>>>(h1, rn1, rowptr, ssrc, h2, rn2, N);
        agnn_kernel<<<blocks, 256, 0, stream>>>(h2, rn2, rowptr, ssrc, h1, rn1, N);
        agnn_kernel<<<blocks, 256, 0, stream>>>(h1, rn1, rowptr, ssrc, h2, rn2, N);
        agnn_kernel<<<blocks, 256, 0, stream>>>(h2, rn2, rowptr, ssrc, h1, rn1, N);
    }

    // lin2 + log_softmax
    lin2_kernel<<<(N + 31) / 32, 256, 0, stream>>>(h1, W2, b2, (float*)d_out, N);
}

// Round 4
// 533.789 us; speedup vs baseline: 1.9880x; 1.1940x over previous
//
#include <hip/hip_runtime.h>
#include <math.h>

#define F_IN 128
#define H_DIM 64
#define C_OUT 40
#define XCDS 8
#define SLICES 96

typedef _Float16 h8 __attribute__((ext_vector_type(8)));  // 16B = 8 fp16 features

// ---------------- CSR build (XCD-partitioned) ----------------

__global__ void __launch_bounds__(256) histx_kernel(const int* __restrict__ dst,
                                                    int* __restrict__ deg, int E, int N) {
    int xcd = blockIdx.x & (XCDS - 1);       // heuristic XCD swizzle (perf only)
    int slice = blockIdx.x >> 3;
    int lo = (int)((long long)N * xcd / XCDS);
    int hi = (int)((long long)N * (xcd + 1) / XCDS);
    int chunk = (E + SLICES - 1) / SLICES;
    int e0 = slice * chunk;
    int e1 = min(E, e0 + chunk);
    for (int e = e0 + (int)threadIdx.x; e < e1; e += 256) {
        int d = dst[e];
        if (d >= lo && d < hi) atomicAdd(&deg[d], 1);
    }
}

__global__ void scan1_kernel(const int* __restrict__ deg, int* __restrict__ incl,
                             int* __restrict__ bsum, int n) {
    __shared__ int s[256];
    int i = blockIdx.x * 256 + threadIdx.x;
    int v = (i < n) ? deg[i] : 0;
    s[threadIdx.x] = v;
    __syncthreads();
#pragma unroll
    for (int off = 1; off < 256; off <<= 1) {
        int t = (threadIdx.x >= off) ? s[threadIdx.x - off] : 0;
        __syncthreads();
        s[threadIdx.x] += t;
        __syncthreads();
    }
    if (i < n) incl[i] = s[threadIdx.x];
    if (threadIdx.x == 255) bsum[blockIdx.x] = s[255];
}

__global__ void scan2_kernel(const int* __restrict__ bsum, int* __restrict__ boff, int nb) {
    __shared__ int s[512];
    int v = ((int)threadIdx.x < nb) ? bsum[threadIdx.x] : 0;
    s[threadIdx.x] = v;
    __syncthreads();
#pragma unroll
    for (int off = 1; off < 512; off <<= 1) {
        int t = (threadIdx.x >= off) ? s[threadIdx.x - off] : 0;
        __syncthreads();
        s[threadIdx.x] += t;
        __syncthreads();
    }
    if ((int)threadIdx.x < nb) boff[threadIdx.x] = s[threadIdx.x] - v;
}

__global__ void scan3_kernel(const int* __restrict__ incl, const int* __restrict__ deg,
                             const int* __restrict__ boff, int* __restrict__ rowptr,
                             int* __restrict__ cursor, int n) {
    int i = blockIdx.x * 256 + threadIdx.x;
    if (i < n) {
        int b = i >> 8;
        int excl = boff[b] + incl[i] - deg[i];
        rowptr[i] = excl;
        cursor[i] = excl;
        if (i == n - 1) rowptr[n] = boff[b] + incl[i];
    }
}

__global__ void __launch_bounds__(256) scatterx_kernel(const int* __restrict__ src,
                                                       const int* __restrict__ dst,
                                                       int* __restrict__ cursor,
                                                       int* __restrict__ ssrc, int E, int N) {
    int xcd = blockIdx.x & (XCDS - 1);
    int slice = blockIdx.x >> 3;
    int lo = (int)((long long)N * xcd / XCDS);
    int hi = (int)((long long)N * (xcd + 1) / XCDS);
    int chunk = (E + SLICES - 1) / SLICES;
    int e0 = slice * chunk;
    int e1 = min(E, e0 + chunk);
    for (int e = e0 + (int)threadIdx.x; e < e1; e += 256) {
        int d = dst[e];
        if (d >= lo && d < hi) {
            int p = atomicAdd(&cursor[d], 1);
            ssrc[p] = src[e];  // p lies in this XCD's contiguous region -> L2-local fill
        }
    }
}

// ---------------- lin1: LDS-staged x tile, 32 rows/block, fp16 h out ----------------
__global__ void __launch_bounds__(256) lin1_kernel(
        const float* __restrict__ x, const float* __restrict__ W1,
        const float* __restrict__ b1, _Float16* __restrict__ hout,
        float* __restrict__ rn, int n) {
    __shared__ float sx[32 * F_IN];  // 16 KB
    int tid = threadIdx.x;
    int r0 = blockIdx.x * 32;
    int rows = min(32, n - r0);

    {
        const float4* xg = (const float4*)(x + (size_t)r0 * F_IN);
        float4* sx4 = (float4*)sx;
        int tot = rows * (F_IN / 4);
        for (int i = tid; i < tot; i += 256) sx4[i] = xg[i];
    }
    __syncthreads();

    int wave = tid >> 6, lane = tid & 63;
    int rbase = wave * 8;
    float bl = b1[lane];
    float acc[8];
#pragma unroll
    for (int j = 0; j < 8; j++) acc[j] = bl;

    const float4* sx4 = (const float4*)sx;
#pragma unroll 2
    for (int k = 0; k < F_IN; k += 4) {
        float w0 = W1[(k + 0) * H_DIM + lane];
        float w1 = W1[(k + 1) * H_DIM + lane];
        float w2 = W1[(k + 2) * H_DIM + lane];
        float w3 = W1[(k + 3) * H_DIM + lane];
#pragma unroll
        for (int j = 0; j < 8; j++) {
            float4 xv = sx4[(rbase + j) * (F_IN / 4) + (k >> 2)];
            acc[j] = fmaf(xv.x, w0, acc[j]);
            acc[j] = fmaf(xv.y, w1, acc[j]);
            acc[j] = fmaf(xv.z, w2, acc[j]);
            acc[j] = fmaf(xv.w, w3, acc[j]);
        }
    }

#pragma unroll
    for (int j = 0; j < 8; j++) {
        int r = rbase + j;
        if (r >= rows) break;
        float a = fmaxf(acc[j], 0.0f);
        hout[(size_t)(r0 + r) * H_DIM + lane] = (_Float16)a;  // coalesced 2B stores
        float ss = a * a;
#pragma unroll
        for (int k = 1; k < 64; k <<= 1) ss += __shfl_xor(ss, k, 64);
        if (lane == 0) rn[r0 + r] = 1.0f / fmaxf(sqrtf(ss), 1e-12f);
    }
}

// ---------------- AGNN layer: wave/dst, 8 lanes/edge (16B fp16 loads), 8 edges in flight ----
__global__ void __launch_bounds__(256) agnn_kernel(
        const h8* __restrict__ h, const float* __restrict__ rnorm,
        const int* __restrict__ rowptr, const int* __restrict__ ssrc,
        h8* __restrict__ hout, float* __restrict__ rnout, int n) {
    int wid = (blockIdx.x * blockDim.x + threadIdx.x) >> 6;
    int t = threadIdx.x & 63;
    if (wid >= n) return;
    int g = t >> 3;    // edge group 0..7
    int sub = t & 7;   // feature chunk (8 halves = 16B)

    h8 hd16 = h[(size_t)wid * 8 + sub];
    float hd[8];
#pragma unroll
    for (int i = 0; i < 8; i++) hd[i] = (float)hd16[i];
    float rni = rnorm[wid];

    float dself = 0.0f;
#pragma unroll
    for (int i = 0; i < 8; i++) dself = fmaf(hd[i], hd[i], dself);
#pragma unroll
    for (int k = 1; k < 8; k <<= 1) dself += __shfl_xor(dself, k, 64);
    float wself = __expf(dself * rni * rni);

    float acc[8];
    float sw = (g == 0) ? wself : 0.0f;
#pragma unroll
    for (int i = 0; i < 8; i++) acc[i] = (g == 0) ? wself * hd[i] : 0.0f;

    int e = rowptr[wid] + g;
    int end = rowptr[wid + 1];

    // 2 edges per group per iteration -> 16 gathers in flight per wave
    for (; e + 8 < end; e += 16) {
        int s0 = ssrc[e];
        int s1 = ssrc[e + 8];
        h8 a16 = h[(size_t)s0 * 8 + sub];
        h8 b16 = h[(size_t)s1 * 8 + sub];
        float rn0 = rnorm[s0];
        float rn1 = rnorm[s1];
        float av[8], bv[8];
#pragma unroll
        for (int i = 0; i < 8; i++) { av[i] = (float)a16[i]; bv[i] = (float)b16[i]; }
        float d0 = 0.0f, d1 = 0.0f;
#pragma unroll
        for (int i = 0; i < 8; i++) { d0 = fmaf(av[i], hd[i], d0); d1 = fmaf(bv[i], hd[i], d1); }
#pragma unroll
        for (int k = 1; k < 8; k <<= 1) {
            d0 += __shfl_xor(d0, k, 64);
            d1 += __shfl_xor(d1, k, 64);
        }
        float w0 = __expf(d0 * rni * rn0);
        float w1 = __expf(d1 * rni * rn1);
#pragma unroll
        for (int i = 0; i < 8; i++) acc[i] = fmaf(w0, av[i], fmaf(w1, bv[i], acc[i]));
        sw += w0 + w1;
    }
    for (; e < end; e += 8) {
        int s0 = ssrc[e];
        h8 a16 = h[(size_t)s0 * 8 + sub];
        float rn0 = rnorm[s0];
        float av[8];
#pragma unroll
        for (int i = 0; i < 8; i++) av[i] = (float)a16[i];
        float d0 = 0.0f;
#pragma unroll
        for (int i = 0; i < 8; i++) d0 = fmaf(av[i], hd[i], d0);
#pragma unroll
        for (int k = 1; k < 8; k <<= 1) d0 += __shfl_xor(d0, k, 64);
        float w0 = __expf(d0 * rni * rn0);
#pragma unroll
        for (int i = 0; i < 8; i++) acc[i] = fmaf(w0, av[i], acc[i]);
        sw += w0;
    }

    // combine the 8 groups
#pragma unroll
    for (int k = 8; k < 64; k <<= 1) {
#pragma unroll
        for (int i = 0; i < 8; i++) acc[i] += __shfl_xor(acc[i], k, 64);
        sw += __shfl_xor(sw, k, 64);
    }
    float inv = 1.0f / sw;
    float o[8];
#pragma unroll
    for (int i = 0; i < 8; i++) o[i] = acc[i] * inv;
    if (g == 0) {
        h8 oh;
#pragma unroll
        for (int i = 0; i < 8; i++) oh[i] = (_Float16)o[i];
        hout[(size_t)wid * 8 + sub] = oh;
    }
    float ss = 0.0f;
#pragma unroll
    for (int i = 0; i < 8; i++) ss = fmaf(o[i], o[i], ss);
#pragma unroll
    for (int k = 1; k < 8; k <<= 1) ss += __shfl_xor(ss, k, 64);
    if (t == 0) rnout[wid] = 1.0f / fmaxf(sqrtf(ss), 1e-12f);
}

// ---------------- lin2 + log_softmax: fp16 input, LDS-staged, 32 rows/block ----------------
__global__ void __launch_bounds__(256) lin2_kernel(
        const h8* __restrict__ h, const float* __restrict__ W2,
        const float* __restrict__ b2, float* __restrict__ out, int n) {
    __shared__ h8 sh[32 * 8];  // 4 KB
    int tid = threadIdx.x;
    int r0 = blockIdx.x * 32;
    int rows = min(32, n - r0);

    {
        const uint4* hg = (const uint4*)(h + (size_t)r0 * 8);
        uint4* sh4 = (uint4*)sh;
        int tot = rows * 8;
        for (int i = tid; i < tot; i += 256) sh4[i] = hg[i];
    }
    __syncthreads();

    int wave = tid >> 6, lane = tid & 63;
    int rbase = wave * 8;

    float acc[8];
    if (lane < C_OUT) {
        float bl = b2[lane];
#pragma unroll
        for (int j = 0; j < 8; j++) acc[j] = bl;
#pragma unroll 2
        for (int k = 0; k < H_DIM; k += 8) {
            float w[8];
#pragma unroll
            for (int i = 0; i < 8; i++) w[i] = W2[(k + i) * C_OUT + lane];
#pragma unroll
            for (int j = 0; j < 8; j++) {
                h8 hv = sh[(rbase + j) * 8 + (k >> 3)];  // broadcast ds_read_b128
#pragma unroll
                for (int i = 0; i < 8; i++) acc[j] = fmaf((float)hv[i], w[i], acc[j]);
            }
        }
    } else {
#pragma unroll
        for (int j = 0; j < 8; j++) acc[j] = -INFINITY;
    }

#pragma unroll
    for (int j = 0; j < 8; j++) {
        int r = rbase + j;
        if (r >= rows) break;
        float m = acc[j];
#pragma unroll
        for (int k = 1; k < 64; k <<= 1) m = fmaxf(m, __shfl_xor(m, k, 64));
        float e = (lane < C_OUT) ? __expf(acc[j] - m) : 0.0f;
        float s = e;
#pragma unroll
        for (int k = 1; k < 64; k <<= 1) s += __shfl_xor(s, k, 64);
        if (lane < C_OUT) out[(size_t)(r0 + r) * C_OUT + lane] = acc[j] - m - logf(s);
    }
}

// ---------------- launch ----------------

extern "C" void kernel_launch(void* const* d_in, const int* in_sizes, int n_in,
                              void* d_out, int out_size, void* d_ws, size_t ws_size,
                              hipStream_t stream) {
    const float* x = (const float*)d_in[0];
    const float* W1 = (const float*)d_in[1];
    const float* b1 = (const float*)d_in[2];
    const float* W2 = (const float*)d_in[3];
    const float* b2 = (const float*)d_in[4];
    const int* ei = (const int*)d_in[5];

    const int N = in_sizes[0] / F_IN;      // 100000
    const int E = in_sizes[5] / 2;         // 1600000
    const int* src = ei;
    const int* dst = ei + E;

    char* w = (char*)d_ws;
    auto carve = [&](size_t bytes) {
        char* p = w;
        w += (bytes + 255) & ~(size_t)255;
        return p;
    };
    _Float16* g1 = (_Float16*)carve((size_t)N * H_DIM * 2);
    _Float16* g2 = (_Float16*)carve((size_t)N * H_DIM * 2);
    float* rn1 = (float*)carve((size_t)N * 4);
    float* rn2 = (float*)carve((size_t)N * 4);
    int* deg = (int*)carve((size_t)N * 4);
    int* incl = (int*)carve((size_t)N * 4);
    int* rowptr = (int*)carve((size_t)(N + 1) * 4);
    int* cursor = (int*)carve((size_t)N * 4);
    int* bsum = (int*)carve(1024 * 4);
    int* boff = (int*)carve(1024 * 4);
    int* ssrc = (int*)carve((size_t)E * 4);

    const int nb = (N + 255) / 256;

    // CSR build (XCD-partitioned hist + scatter)
    hipMemsetAsync(deg, 0, (size_t)N * 4, stream);
    histx_kernel<<<XCDS * SLICES, 256, 0, stream>>>(dst, deg, E, N);
    scan1_kernel<<<nb, 256, 0, stream>>>(deg, incl, bsum, N);
    scan2_kernel<<<1, 512, 0, stream>>>(bsum, boff, nb);
    scan3_kernel<<<nb, 256, 0, stream>>>(incl, deg, boff, rowptr, cursor, N);
    scatterx_kernel<<<XCDS * SLICES, 256, 0, stream>>>(src, dst, cursor, ssrc, E, N);

    // lin1 (+rnorm), fp16 h out
    lin1_kernel<<<(N + 31) / 32, 256, 0, stream>>>(x, W1, b1, g1, rn1, N);

    // 4 AGNN layers, ping-pong on fp16 h
    {
        int blocks = (N * 64 + 255) / 256;
        agnn_kernel<<<blocks, 256, 0, stream>>>((const h8*)g1, rn1, rowptr, ssrc, (h8*)g2, rn2, N);
        agnn_kernel<<<blocks, 256, 0, stream>>>((const h8*)g2, rn2, rowptr, ssrc, (h8*)g1, rn1, N);
        agnn_kernel<<<blocks, 256, 0, stream>>>((const h8*)g1, rn1, rowptr, ssrc, (h8*)g2, rn2, N);
        agnn_kernel<<<blocks, 256, 0, stream>>>((const h8*)g2, rn2, rowptr, ssrc, (h8*)g1, rn1, N);
    }

    // lin2 + log_softmax
    lin2_kernel<<<(N + 31) / 32, 256, 0, stream>>>((const h8*)g1, W2, b2, (float*)d_out, N);
}